// Round 1
// baseline (562.474 us; speedup 1.0000x reference)
//
#include <hip/hip_runtime.h>
#include <stdint.h>

// Link predictor: score[e] = MLP([src,dst,src*dst,|src-dst|]) over 500K edges.
// bf16 MFMA (16x16x32) for GEMM1/GEMM2, fp32 bias/relu/final dot.
// d_ws: stage1 = W1 bf16 in B-frag layout (65536 shorts), stage2 = W2 (8192 shorts).

typedef __bf16 bf16x8 __attribute__((ext_vector_type(8)));
typedef float  f32x4  __attribute__((ext_vector_type(4)));
typedef short  s16x4  __attribute__((ext_vector_type(4)));

__device__ __forceinline__ short f2bf(float f) {
    union { float f; uint32_t u; } v; v.f = f;
    uint32_t u = v.u;
    uint32_t r = (u + 0x7fffu + ((u >> 16) & 1u)) >> 16;   // RNE
    return (short)r;
}

// ---------------- prep: W1/W2 fp32 -> bf16 B-fragment layout ----------------
// stage1[((ntile*16+kstep)*64+lane)*8+j] = bf16(W1[(kstep*32+(lane>>4)*8+j)*128 + ntile*16+(lane&15)])
// stage2[((ntile*4 +kstep)*64+lane)*8+j] = bf16(W2[(kstep*32+(lane>>4)*8+j)*64  + ntile*16+(lane&15)])
__global__ void prep_kernel(const float* __restrict__ W1, const float* __restrict__ W2,
                            short* __restrict__ stage1, short* __restrict__ stage2) {
    int idx = blockIdx.x * 256 + threadIdx.x;
    if (idx < 65536) {
        int j = idx & 7;
        int lane = (idx >> 3) & 63;
        int t = idx >> 9;            // ntile*16 + kstep
        int kstep = t & 15;
        int ntile = t >> 4;
        int k = kstep * 32 + ((lane >> 4) & 3) * 8 + j;
        int n = ntile * 16 + (lane & 15);
        stage1[idx] = f2bf(W1[k * 128 + n]);
    } else if (idx < 65536 + 8192) {
        int i2 = idx - 65536;
        int j = i2 & 7;
        int lane = (i2 >> 3) & 63;
        int t = i2 >> 9;             // ntile*4 + kstep
        int kstep = t & 3;
        int ntile = t >> 2;
        int k = kstep * 32 + ((lane >> 4) & 3) * 8 + j;
        int n = ntile * 16 + (lane & 15);
        stage2[i2] = f2bf(W2[k * 64 + n]);
    }
}

// ---------------- main ----------------
// 64 edges/block, 256 threads (4 waves).
// LDS 64KB: phase A = bf16 A-tile [64 rows x 512 k], row stride 1024B,
//   16B-chunk cc = k>>3 stored at physical chunk cc ^ (m&7)  (XOR swizzle).
// After GEMM1: bytes [0,16384) reused for h1 bf16 [64 x 128] (same swizzle, stride 256B).
// After GEMM2: bytes [32768, ...) hold h2 fp32 [64 x 68] (stride 272B).
__launch_bounds__(256, 2)
__global__ void link_kernel(const float* __restrict__ z,
                            const int*   __restrict__ ei,
                            const float* __restrict__ b1,
                            const float* __restrict__ b2,
                            const float* __restrict__ w3,
                            const float* __restrict__ b3,
                            const short* __restrict__ stage1,
                            const short* __restrict__ stage2,
                            float* __restrict__ out,
                            int E) {
    __shared__ __align__(16) char smem[65536];

    const int tid  = threadIdx.x;
    const int lane = tid & 63;
    const int wave = tid >> 6;
    const int ln15 = lane & 15;
    const int quad = lane >> 4;
    const int e0   = blockIdx.x * 64;

    // ---- Phase A: gather + feature build -> LDS (bf16, swizzled) ----
    #pragma unroll
    for (int i = 0; i < 8; ++i) {
        int q = i * 256 + tid;
        int m = q >> 5;           // edge row 0..63
        int c = q & 31;           // float4 chunk 0..31 (covers 128 floats)
        int eg = e0 + m;
        bool valid = eg < E;
        int si = valid ? ei[eg] : 0;
        int di = valid ? ei[E + eg] : 0;
        f32x4 s = *(const f32x4*)(z + (size_t)si * 128 + c * 4);
        f32x4 d = *(const f32x4*)(z + (size_t)di * 128 + c * 4);
        f32x4 it = s * d;
        f32x4 df;
        df[0] = __builtin_fabsf(s[0] - d[0]);
        df[1] = __builtin_fabsf(s[1] - d[1]);
        df[2] = __builtin_fabsf(s[2] - d[2]);
        df[3] = __builtin_fabsf(s[3] - d[3]);

        int k0 = c * 4;
        #pragma unroll
        for (int blk = 0; blk < 4; ++blk) {
            f32x4 v = (blk == 0) ? s : (blk == 1) ? d : (blk == 2) ? it : df;
            int k = k0 + blk * 128;
            int cc = k >> 3;
            int half = (k >> 2) & 1;
            int addr = m * 1024 + ((cc ^ (m & 7)) << 4) + half * 8;
            s16x4 p;
            p[0] = f2bf(v[0]); p[1] = f2bf(v[1]); p[2] = f2bf(v[2]); p[3] = f2bf(v[3]);
            *(s16x4*)(smem + addr) = p;
        }
    }
    __syncthreads();

    // ---- GEMM1: [64x512]bf16 @ W1[512x128] -> acc fp32 ----
    // wave w owns output cols [32w, 32w+32) as 2 n-tiles; 4 m-tiles of 16 edges.
    f32x4 acc[4][2];
    #pragma unroll
    for (int mt = 0; mt < 4; ++mt)
        #pragma unroll
        for (int nt = 0; nt < 2; ++nt)
            acc[mt][nt] = (f32x4){0.f, 0.f, 0.f, 0.f};

    for (int ks = 0; ks < 16; ++ks) {
        bf16x8 a[4];
        #pragma unroll
        for (int mt = 0; mt < 4; ++mt) {
            int m = mt * 16 + ln15;
            int cc = ks * 4 + quad;
            a[mt] = *(const bf16x8*)(smem + m * 1024 + ((cc ^ (m & 7)) << 4));
        }
        #pragma unroll
        for (int nt = 0; nt < 2; ++nt) {
            int ntile = wave * 2 + nt;
            bf16x8 b = *(const bf16x8*)(stage1 + (((ntile * 16 + ks) * 64 + lane) << 3));
            #pragma unroll
            for (int mt = 0; mt < 4; ++mt)
                acc[mt][nt] = __builtin_amdgcn_mfma_f32_16x16x32_bf16(a[mt], b, acc[mt][nt], 0, 0, 0);
        }
    }
    __syncthreads();   // all waves done reading A-tile

    // ---- epilogue 1: h1 = relu(acc + b1) -> LDS bf16 [64 x 128], swizzled, stride 256B ----
    #pragma unroll
    for (int nt = 0; nt < 2; ++nt) {
        int n = (wave * 2 + nt) * 16 + ln15;      // = k2 for GEMM2
        float bias = b1[n];
        #pragma unroll
        for (int mt = 0; mt < 4; ++mt) {
            #pragma unroll
            for (int r = 0; r < 4; ++r) {
                int row = mt * 16 + quad * 4 + r;  // C/D: row = quad*4 + reg
                float h = acc[mt][nt][r] + bias;
                h = h > 0.f ? h : 0.f;
                int addr = row * 256 + (((n >> 3) ^ (row & 7)) << 4) + (n & 7) * 2;
                *(short*)(smem + addr) = f2bf(h);
            }
        }
    }
    __syncthreads();

    // ---- GEMM2: h1[64x128] @ W2[128x64]; wave w owns n-tile w (16 cols) ----
    f32x4 acc2[4];
    #pragma unroll
    for (int mt = 0; mt < 4; ++mt) acc2[mt] = (f32x4){0.f, 0.f, 0.f, 0.f};

    #pragma unroll
    for (int ks = 0; ks < 4; ++ks) {
        bf16x8 b = *(const bf16x8*)(stage2 + (((wave * 4 + ks) * 64 + lane) << 3));
        #pragma unroll
        for (int mt = 0; mt < 4; ++mt) {
            int m = mt * 16 + ln15;
            int cc = ks * 4 + quad;
            bf16x8 a = *(const bf16x8*)(smem + m * 256 + ((cc ^ (m & 7)) << 4));
            acc2[mt] = __builtin_amdgcn_mfma_f32_16x16x32_bf16(a, b, acc2[mt], 0, 0, 0);
        }
    }

    // ---- epilogue 2: h2 = relu(acc2 + b2) -> LDS fp32 [64 x 68] at +32KB ----
    {
        int n2 = wave * 16 + ln15;
        float bias = b2[n2];
        #pragma unroll
        for (int mt = 0; mt < 4; ++mt) {
            #pragma unroll
            for (int r = 0; r < 4; ++r) {
                int row = mt * 16 + quad * 4 + r;
                float h = acc2[mt][r] + bias;
                h = h > 0.f ? h : 0.f;
                *(float*)(smem + 32768 + row * 272 + n2 * 4) = h;
            }
        }
    }
    __syncthreads();

    // ---- final: score = h2 . W3 + b3 (fp32), wave 0, one lane per edge ----
    if (wave == 0) {
        int e = lane;
        float accf = b3[0];
        const float* h2p = (const float*)(smem + 32768 + e * 272);
        #pragma unroll
        for (int kk = 0; kk < 16; ++kk) {
            f32x4 h = *(const f32x4*)(h2p + kk * 4);
            f32x4 w = *(const f32x4*)(w3 + kk * 4);
            accf += h[0] * w[0] + h[1] * w[1] + h[2] * w[2] + h[3] * w[3];
        }
        if (e0 + e < E) out[e0 + e] = accf;
    }
}

extern "C" void kernel_launch(void* const* d_in, const int* in_sizes, int n_in,
                              void* d_out, int out_size, void* d_ws, size_t ws_size,
                              hipStream_t stream) {
    const float* z  = (const float*)d_in[0];
    const int*   ei = (const int*)  d_in[1];
    const float* W1 = (const float*)d_in[2];
    const float* b1 = (const float*)d_in[3];
    const float* W2 = (const float*)d_in[4];
    const float* b2 = (const float*)d_in[5];
    const float* W3 = (const float*)d_in[6];
    const float* b3 = (const float*)d_in[7];
    float* out = (float*)d_out;

    int E = in_sizes[1] / 2;

    short* stage1 = (short*)d_ws;          // 65536 shorts = 128 KB
    short* stage2 = stage1 + 65536;        // 8192 shorts  = 16 KB

    prep_kernel<<<288, 256, 0, stream>>>(W1, W2, stage1, stage2);

    int nblk = (E + 63) / 64;
    link_kernel<<<nblk, 256, 0, stream>>>(z, ei, b1, b2, W3, b3, stage1, stage2, out, E);
}

// Round 2
// 493.077 us; speedup vs baseline: 1.1407x; 1.1407x over previous
//
#include <hip/hip_runtime.h>
#include <stdint.h>

// Link predictor: score[e] = MLP([src,dst,src*dst,|src-dst|]) over 500K edges.
// Round 2: stage only s,d tiles in LDS (32KB -> 5 blocks/CU, 62.5% occupancy);
// derive interaction/difference A-fragments in registers inside GEMM1.
// d_ws: stage1 = W1 bf16 B-frag layout (65536 shorts), stage2 = W2 (8192 shorts).

typedef __bf16 bf16x8 __attribute__((ext_vector_type(8)));
typedef __bf16 bf16x4 __attribute__((ext_vector_type(4)));
typedef float  f32x4  __attribute__((ext_vector_type(4)));

__device__ __forceinline__ short f2bf(float f) {
    union { float f; uint32_t u; } v; v.f = f;
    uint32_t u = v.u;
    uint32_t r = (u + 0x7fffu + ((u >> 16) & 1u)) >> 16;   // RNE
    return (short)r;
}

// ---------------- prep: W1/W2 fp32 -> bf16 B-fragment layout ----------------
// Coalesced reads (idx linear over W row-major), scattered 2B writes (tiny total).
// stage1[((ntile*16+kstep)*64+lane)*8+j] = bf16(W1[k*128+n]),
//   k = kstep*32 + (lane>>4)*8 + j, n = ntile*16 + (lane&15).
__global__ void prep_kernel(const float* __restrict__ W1, const float* __restrict__ W2,
                            short* __restrict__ stage1, short* __restrict__ stage2) {
    int idx = blockIdx.x * 256 + threadIdx.x;
    if (idx < 65536) {
        int k = idx >> 7, n = idx & 127;
        float v = W1[idx];
        int ntile = n >> 4, ln = n & 15;
        int kstep = k >> 5, kr = k & 31;
        int lane = (kr >> 3) * 16 + ln;
        int j = kr & 7;
        stage1[(((ntile * 16 + kstep) * 64 + lane) << 3) + j] = f2bf(v);
    } else if (idx < 65536 + 8192) {
        int i2 = idx - 65536;
        int k = i2 >> 6, n = i2 & 63;
        float v = W2[i2];
        int ntile = n >> 4, ln = n & 15;
        int kstep = k >> 5, kr = k & 31;
        int lane = (kr >> 3) * 16 + ln;
        int j = kr & 7;
        stage2[(((ntile * 4 + kstep) * 64 + lane) << 3) + j] = f2bf(v);
    }
}

// ---------------- main ----------------
// 64 edges/block, 256 threads (4 waves), 32KB LDS -> 5 blocks/CU.
// LDS: s-tile [64 x 128]bf16 at 0 (stride 256B), d-tile at 16384.
//   16B chunk cc = k>>3 stored at physical chunk cc ^ (m&15) (XOR swizzle).
// After GEMM1: [0,16384) reused for h1 bf16 [64x128] (same swizzle).
// After GEMM2: [0,17408) holds h2 fp32 [64 x 68] (stride 272B).
__launch_bounds__(256, 5)
__global__ void link_kernel(const float* __restrict__ z,
                            const int*   __restrict__ ei,
                            const float* __restrict__ b1,
                            const float* __restrict__ b2,
                            const float* __restrict__ w3,
                            const float* __restrict__ b3,
                            const short* __restrict__ stage1,
                            const short* __restrict__ stage2,
                            float* __restrict__ out,
                            int E) {
    __shared__ __align__(16) char smem[32768];

    const int tid  = threadIdx.x;
    const int lane = tid & 63;
    const int wave = tid >> 6;
    const int ln15 = lane & 15;
    const int quad = lane >> 4;
    const int e0   = blockIdx.x * 64;

    // ---- Phase A: gather src/dst rows -> LDS bf16 (swizzled) ----
    // Each thread: fixed float4-chunk c = tid&31; rows m = (tid>>5) + 8i.
    const int c    = tid & 31;
    const int mrow = tid >> 5;
    int si[8], di[8];
    #pragma unroll
    for (int i = 0; i < 8; ++i) {
        int eg = e0 + mrow + i * 8;
        int egc = eg < E ? eg : (E - 1);
        si[i] = ei[egc];
        di[i] = ei[E + egc];
    }
    const int cc   = c >> 1;
    const int half = c & 1;
    #pragma unroll
    for (int i = 0; i < 8; ++i) {
        int m = mrow + i * 8;
        f32x4 s = *(const f32x4*)(z + (size_t)si[i] * 128 + c * 4);
        f32x4 d = *(const f32x4*)(z + (size_t)di[i] * 128 + c * 4);
        int addr = m * 256 + ((cc ^ (m & 15)) << 4) + half * 8;
        bf16x4 ps, pd;
        #pragma unroll
        for (int j = 0; j < 4; ++j) { ps[j] = (__bf16)s[j]; pd[j] = (__bf16)d[j]; }
        *(bf16x4*)(smem + addr)         = ps;
        *(bf16x4*)(smem + 16384 + addr) = pd;
    }
    __syncthreads();

    // ---- GEMM1: A[64x512] @ W1[512x128], A-frags for feature blocks 2,3 derived in regs ----
    f32x4 acc[4][2];
    #pragma unroll
    for (int mt = 0; mt < 4; ++mt)
        #pragma unroll
        for (int nt = 0; nt < 2; ++nt)
            acc[mt][nt] = (f32x4){0.f, 0.f, 0.f, 0.f};

    #pragma unroll
    for (int ks4 = 0; ks4 < 4; ++ks4) {
        bf16x8 B[2][4];
        #pragma unroll
        for (int nt = 0; nt < 2; ++nt) {
            int ntile = wave * 2 + nt;
            #pragma unroll
            for (int f = 0; f < 4; ++f)
                B[nt][f] = *(const bf16x8*)(stage1 + (((ntile * 16 + f * 4 + ks4) * 64 + lane) << 3));
        }
        #pragma unroll
        for (int mt = 0; mt < 4; ++mt) {
            int m = mt * 16 + ln15;
            int off = m * 256 + ((((ks4 * 4 + quad)) ^ (m & 15)) << 4);
            bf16x8 sf = *(const bf16x8*)(smem + off);
            bf16x8 df = *(const bf16x8*)(smem + 16384 + off);
            bf16x8 itf, ddf;
            #pragma unroll
            for (int j = 0; j < 8; ++j) {
                float fs = (float)sf[j], fd = (float)df[j];
                itf[j] = (__bf16)(fs * fd);
                ddf[j] = (__bf16)__builtin_fabsf(fs - fd);
            }
            #pragma unroll
            for (int nt = 0; nt < 2; ++nt) {
                acc[mt][nt] = __builtin_amdgcn_mfma_f32_16x16x32_bf16(sf,  B[nt][0], acc[mt][nt], 0, 0, 0);
                acc[mt][nt] = __builtin_amdgcn_mfma_f32_16x16x32_bf16(df,  B[nt][1], acc[mt][nt], 0, 0, 0);
                acc[mt][nt] = __builtin_amdgcn_mfma_f32_16x16x32_bf16(itf, B[nt][2], acc[mt][nt], 0, 0, 0);
                acc[mt][nt] = __builtin_amdgcn_mfma_f32_16x16x32_bf16(ddf, B[nt][3], acc[mt][nt], 0, 0, 0);
            }
        }
    }
    __syncthreads();   // all waves done reading s/d tiles

    // ---- epilogue 1: h1 = relu(acc + b1) -> LDS bf16 [64 x 128] at 0, swizzled ----
    #pragma unroll
    for (int nt = 0; nt < 2; ++nt) {
        int n = (wave * 2 + nt) * 16 + ln15;      // = k2 for GEMM2
        float bias = b1[n];
        #pragma unroll
        for (int mt = 0; mt < 4; ++mt) {
            #pragma unroll
            for (int r = 0; r < 4; ++r) {
                int row = mt * 16 + quad * 4 + r;  // C/D: row = quad*4 + reg
                float h = acc[mt][nt][r] + bias;
                h = h > 0.f ? h : 0.f;
                int addr = row * 256 + (((n >> 3) ^ (row & 15)) << 4) + (n & 7) * 2;
                *(short*)(smem + addr) = f2bf(h);
            }
        }
    }
    __syncthreads();

    // ---- GEMM2: h1[64x128] @ W2[128x64]; wave w owns n-tile w (16 cols) ----
    f32x4 acc2[4];
    #pragma unroll
    for (int mt = 0; mt < 4; ++mt) acc2[mt] = (f32x4){0.f, 0.f, 0.f, 0.f};

    #pragma unroll
    for (int ks = 0; ks < 4; ++ks) {
        bf16x8 b = *(const bf16x8*)(stage2 + (((wave * 4 + ks) * 64 + lane) << 3));
        #pragma unroll
        for (int mt = 0; mt < 4; ++mt) {
            int m = mt * 16 + ln15;
            int ccr = ks * 4 + quad;
            bf16x8 a = *(const bf16x8*)(smem + m * 256 + ((ccr ^ (m & 15)) << 4));
            acc2[mt] = __builtin_amdgcn_mfma_f32_16x16x32_bf16(a, b, acc2[mt], 0, 0, 0);
        }
    }
    __syncthreads();   // all waves done reading h1

    // ---- epilogue 2: h2 = relu(acc2 + b2) -> LDS fp32 [64 x 68] at 0 ----
    {
        int n2 = wave * 16 + ln15;
        float bias = b2[n2];
        #pragma unroll
        for (int mt = 0; mt < 4; ++mt) {
            #pragma unroll
            for (int r = 0; r < 4; ++r) {
                int row = mt * 16 + quad * 4 + r;
                float h = acc2[mt][r] + bias;
                h = h > 0.f ? h : 0.f;
                *(float*)(smem + row * 272 + n2 * 4) = h;
            }
        }
    }
    __syncthreads();

    // ---- final: score = h2 . W3 + b3 (fp32), wave 0, one lane per edge ----
    if (wave == 0) {
        int e = lane;
        float accf = b3[0];
        const float* h2p = (const float*)(smem + e * 272);
        #pragma unroll
        for (int kk = 0; kk < 16; ++kk) {
            f32x4 h = *(const f32x4*)(h2p + kk * 4);
            f32x4 w = *(const f32x4*)(w3 + kk * 4);
            accf += h[0] * w[0] + h[1] * w[1] + h[2] * w[2] + h[3] * w[3];
        }
        if (e0 + e < E) out[e0 + e] = accf;
    }
}

extern "C" void kernel_launch(void* const* d_in, const int* in_sizes, int n_in,
                              void* d_out, int out_size, void* d_ws, size_t ws_size,
                              hipStream_t stream) {
    const float* z  = (const float*)d_in[0];
    const int*   ei = (const int*)  d_in[1];
    const float* W1 = (const float*)d_in[2];
    const float* b1 = (const float*)d_in[3];
    const float* W2 = (const float*)d_in[4];
    const float* b2 = (const float*)d_in[5];
    const float* W3 = (const float*)d_in[6];
    const float* b3 = (const float*)d_in[7];
    float* out = (float*)d_out;

    int E = in_sizes[1] / 2;

    short* stage1 = (short*)d_ws;          // 65536 shorts = 128 KB
    short* stage2 = stage1 + 65536;        // 8192 shorts  = 16 KB

    prep_kernel<<<288, 256, 0, stream>>>(W1, W2, stage1, stage2);

    int nblk = (E + 63) / 64;
    link_kernel<<<nblk, 256, 0, stream>>>(z, ei, b1, b2, W3, b3, stage1, stage2, out, E);
}

// Round 3
// 429.034 us; speedup vs baseline: 1.3110x; 1.1493x over previous
//
#include <hip/hip_runtime.h>
#include <stdint.h>

// Link predictor: score[e] = MLP([src,dst,src*dst,|src-dst|]) over 500K edges.
// Round 3: same structure as round 2 (32KB LDS, s/d tiles staged, it/df derived
// in regs) but __launch_bounds__(256,4): round 2's (256,5) capped VGPRs at ~102
// and the compiler spilled to scratch (WRITE_SIZE 220MB, VGPR_Count=48).
// 128-VGPR cap removes the spill; LDS allows 5 blocks but VGPR allows 4 -> 50% occ.
// d_ws: stage1 = W1 bf16 B-frag layout (65536 shorts), stage2 = W2 (8192 shorts).

typedef __bf16 bf16x8 __attribute__((ext_vector_type(8)));
typedef __bf16 bf16x4 __attribute__((ext_vector_type(4)));
typedef float  f32x4  __attribute__((ext_vector_type(4)));

__device__ __forceinline__ short f2bf(float f) {
    union { float f; uint32_t u; } v; v.f = f;
    uint32_t u = v.u;
    uint32_t r = (u + 0x7fffu + ((u >> 16) & 1u)) >> 16;   // RNE
    return (short)r;
}

// ---------------- prep: W1/W2 fp32 -> bf16 B-fragment layout ----------------
// stage1[((ntile*16+kstep)*64+lane)*8+j] = bf16(W1[k*128+n]),
//   k = kstep*32 + (lane>>4)*8 + j, n = ntile*16 + (lane&15).
__global__ void prep_kernel(const float* __restrict__ W1, const float* __restrict__ W2,
                            short* __restrict__ stage1, short* __restrict__ stage2) {
    int idx = blockIdx.x * 256 + threadIdx.x;
    if (idx < 65536) {
        int k = idx >> 7, n = idx & 127;
        float v = W1[idx];
        int ntile = n >> 4, ln = n & 15;
        int kstep = k >> 5, kr = k & 31;
        int lane = (kr >> 3) * 16 + ln;
        int j = kr & 7;
        stage1[(((ntile * 16 + kstep) * 64 + lane) << 3) + j] = f2bf(v);
    } else if (idx < 65536 + 8192) {
        int i2 = idx - 65536;
        int k = i2 >> 6, n = i2 & 63;
        float v = W2[i2];
        int ntile = n >> 4, ln = n & 15;
        int kstep = k >> 5, kr = k & 31;
        int lane = (kr >> 3) * 16 + ln;
        int j = kr & 7;
        stage2[(((ntile * 4 + kstep) * 64 + lane) << 3) + j] = f2bf(v);
    }
}

// ---------------- main ----------------
// 64 edges/block, 256 threads (4 waves), 32KB LDS.
// LDS: s-tile [64 x 128]bf16 at 0 (stride 256B), d-tile at 16384.
//   16B chunk cc = k>>3 stored at physical chunk cc ^ (m&15) (XOR swizzle).
// After GEMM1: [0,16384) reused for h1 bf16 [64x128] (same swizzle).
// After GEMM2: [0,17408) holds h2 fp32 [64 x 68] (stride 272B).
__launch_bounds__(256, 4)
__global__ void link_kernel(const float* __restrict__ z,
                            const int*   __restrict__ ei,
                            const float* __restrict__ b1,
                            const float* __restrict__ b2,
                            const float* __restrict__ w3,
                            const float* __restrict__ b3,
                            const short* __restrict__ stage1,
                            const short* __restrict__ stage2,
                            float* __restrict__ out,
                            int E) {
    __shared__ __align__(16) char smem[32768];

    const int tid  = threadIdx.x;
    const int lane = tid & 63;
    const int wave = tid >> 6;
    const int ln15 = lane & 15;
    const int quad = lane >> 4;
    const int e0   = blockIdx.x * 64;

    // ---- Phase A: gather src/dst rows -> LDS bf16 (swizzled) ----
    // Each thread: fixed float4-chunk c = tid&31; rows m = (tid>>5) + 8i.
    const int c    = tid & 31;
    const int mrow = tid >> 5;
    int si[8], di[8];
    #pragma unroll
    for (int i = 0; i < 8; ++i) {
        int eg = e0 + mrow + i * 8;
        int egc = eg < E ? eg : (E - 1);
        si[i] = ei[egc];
        di[i] = ei[E + egc];
    }
    const int cc   = c >> 1;
    const int half = c & 1;
    #pragma unroll
    for (int i = 0; i < 8; ++i) {
        int m = mrow + i * 8;
        f32x4 s = *(const f32x4*)(z + (size_t)si[i] * 128 + c * 4);
        f32x4 d = *(const f32x4*)(z + (size_t)di[i] * 128 + c * 4);
        int addr = m * 256 + ((cc ^ (m & 15)) << 4) + half * 8;
        bf16x4 ps, pd;
        #pragma unroll
        for (int j = 0; j < 4; ++j) { ps[j] = (__bf16)s[j]; pd[j] = (__bf16)d[j]; }
        *(bf16x4*)(smem + addr)         = ps;
        *(bf16x4*)(smem + 16384 + addr) = pd;
    }
    __syncthreads();

    // ---- GEMM1: A[64x512] @ W1[512x128], it/df A-frags derived in regs ----
    f32x4 acc[4][2];
    #pragma unroll
    for (int mt = 0; mt < 4; ++mt)
        #pragma unroll
        for (int nt = 0; nt < 2; ++nt)
            acc[mt][nt] = (f32x4){0.f, 0.f, 0.f, 0.f};

    #pragma unroll
    for (int ks4 = 0; ks4 < 4; ++ks4) {
        bf16x8 B[2][4];
        #pragma unroll
        for (int nt = 0; nt < 2; ++nt) {
            int ntile = wave * 2 + nt;
            #pragma unroll
            for (int f = 0; f < 4; ++f)
                B[nt][f] = *(const bf16x8*)(stage1 + (((ntile * 16 + f * 4 + ks4) * 64 + lane) << 3));
        }
        #pragma unroll
        for (int mt = 0; mt < 4; ++mt) {
            int m = mt * 16 + ln15;
            int off = m * 256 + ((((ks4 * 4 + quad)) ^ (m & 15)) << 4);
            bf16x8 sf = *(const bf16x8*)(smem + off);
            bf16x8 df = *(const bf16x8*)(smem + 16384 + off);
            bf16x8 itf, ddf;
            #pragma unroll
            for (int j = 0; j < 8; ++j) {
                float fs = (float)sf[j], fd = (float)df[j];
                itf[j] = (__bf16)(fs * fd);
                ddf[j] = (__bf16)__builtin_fabsf(fs - fd);
            }
            #pragma unroll
            for (int nt = 0; nt < 2; ++nt) {
                acc[mt][nt] = __builtin_amdgcn_mfma_f32_16x16x32_bf16(sf,  B[nt][0], acc[mt][nt], 0, 0, 0);
                acc[mt][nt] = __builtin_amdgcn_mfma_f32_16x16x32_bf16(df,  B[nt][1], acc[mt][nt], 0, 0, 0);
                acc[mt][nt] = __builtin_amdgcn_mfma_f32_16x16x32_bf16(itf, B[nt][2], acc[mt][nt], 0, 0, 0);
                acc[mt][nt] = __builtin_amdgcn_mfma_f32_16x16x32_bf16(ddf, B[nt][3], acc[mt][nt], 0, 0, 0);
            }
        }
    }
    __syncthreads();   // all waves done reading s/d tiles

    // ---- epilogue 1: h1 = relu(acc + b1) -> LDS bf16 [64 x 128] at 0, swizzled ----
    #pragma unroll
    for (int nt = 0; nt < 2; ++nt) {
        int n = (wave * 2 + nt) * 16 + ln15;      // = k2 for GEMM2
        float bias = b1[n];
        #pragma unroll
        for (int mt = 0; mt < 4; ++mt) {
            #pragma unroll
            for (int r = 0; r < 4; ++r) {
                int row = mt * 16 + quad * 4 + r;  // C/D: row = quad*4 + reg
                float h = acc[mt][nt][r] + bias;
                h = h > 0.f ? h : 0.f;
                int addr = row * 256 + (((n >> 3) ^ (row & 15)) << 4) + (n & 7) * 2;
                *(short*)(smem + addr) = f2bf(h);
            }
        }
    }
    __syncthreads();

    // ---- GEMM2: h1[64x128] @ W2[128x64]; wave w owns n-tile w (16 cols) ----
    f32x4 acc2[4];
    #pragma unroll
    for (int mt = 0; mt < 4; ++mt) acc2[mt] = (f32x4){0.f, 0.f, 0.f, 0.f};

    #pragma unroll
    for (int ks = 0; ks < 4; ++ks) {
        bf16x8 b = *(const bf16x8*)(stage2 + (((wave * 4 + ks) * 64 + lane) << 3));
        #pragma unroll
        for (int mt = 0; mt < 4; ++mt) {
            int m = mt * 16 + ln15;
            int ccr = ks * 4 + quad;
            bf16x8 a = *(const bf16x8*)(smem + m * 256 + ((ccr ^ (m & 15)) << 4));
            acc2[mt] = __builtin_amdgcn_mfma_f32_16x16x32_bf16(a, b, acc2[mt], 0, 0, 0);
        }
    }
    __syncthreads();   // all waves done reading h1

    // ---- epilogue 2: h2 = relu(acc2 + b2) -> LDS fp32 [64 x 68] at 0 ----
    {
        int n2 = wave * 16 + ln15;
        float bias = b2[n2];
        #pragma unroll
        for (int mt = 0; mt < 4; ++mt) {
            #pragma unroll
            for (int r = 0; r < 4; ++r) {
                int row = mt * 16 + quad * 4 + r;
                float h = acc2[mt][r] + bias;
                h = h > 0.f ? h : 0.f;
                *(float*)(smem + row * 272 + n2 * 4) = h;
            }
        }
    }
    __syncthreads();

    // ---- final: score = h2 . W3 + b3 (fp32), wave 0, one lane per edge ----
    if (wave == 0) {
        int e = lane;
        float accf = b3[0];
        const float* h2p = (const float*)(smem + e * 272);
        #pragma unroll
        for (int kk = 0; kk < 16; ++kk) {
            f32x4 h = *(const f32x4*)(h2p + kk * 4);
            f32x4 w = *(const f32x4*)(w3 + kk * 4);
            accf += h[0] * w[0] + h[1] * w[1] + h[2] * w[2] + h[3] * w[3];
        }
        if (e0 + e < E) out[e0 + e] = accf;
    }
}

extern "C" void kernel_launch(void* const* d_in, const int* in_sizes, int n_in,
                              void* d_out, int out_size, void* d_ws, size_t ws_size,
                              hipStream_t stream) {
    const float* z  = (const float*)d_in[0];
    const int*   ei = (const int*)  d_in[1];
    const float* W1 = (const float*)d_in[2];
    const float* b1 = (const float*)d_in[3];
    const float* W2 = (const float*)d_in[4];
    const float* b2 = (const float*)d_in[5];
    const float* W3 = (const float*)d_in[6];
    const float* b3 = (const float*)d_in[7];
    float* out = (float*)d_out;

    int E = in_sizes[1] / 2;

    short* stage1 = (short*)d_ws;          // 65536 shorts = 128 KB
    short* stage2 = stage1 + 65536;        // 8192 shorts  = 16 KB

    prep_kernel<<<288, 256, 0, stream>>>(W1, W2, stage1, stage2);

    int nblk = (E + 63) / 64;
    link_kernel<<<nblk, 256, 0, stream>>>(z, ei, b1, b2, W3, b3, stage1, stage2, out, E);
}